// Round 1
// baseline (299.875 us; speedup 1.0000x reference)
//
#include <hip/hip_runtime.h>
#include <hip/hip_bf16.h>

#define VOCAB 50257
#define DIM   1024
#define R     16
#define SCALING 2.0f
#define TPB   8   // tokens per block

__global__ __launch_bounds__(256) void adapted_embedding_kernel(
    const int*   __restrict__ ids,
    const float* __restrict__ emb,
    const float* __restrict__ A,    // [R, VOCAB]
    const float* __restrict__ B,    // [DIM, R]
    float*       __restrict__ out,  // [n_tokens, DIM]
    int n_tokens)
{
    __shared__ float sA[TPB][R];
    __shared__ int   sT[TPB];

    const int tid      = threadIdx.x;
    const int base_tok = blockIdx.x * TPB;

    // Stage token ids
    if (tid < TPB) {
        int g = base_tok + tid;
        sT[tid] = (g < n_tokens) ? ids[g] : 0;
    }
    __syncthreads();

    // Stage lora_A columns for the 8 tokens: 128 scalars, threads 0..127
    if (tid < TPB * R) {
        int ti = tid / R;
        int r  = tid % R;
        sA[ti][r] = A[(size_t)r * VOCAB + sT[ti]];
    }

    // Each thread owns d in [4*tid, 4*tid+4): load its 4 lora_B rows (64 floats)
    const int d0 = tid * 4;
    const float4* B4 = reinterpret_cast<const float4*>(B);
    float4 b[16];
    #pragma unroll
    for (int k = 0; k < 4; ++k)
        #pragma unroll
        for (int q = 0; q < 4; ++q)
            b[k * 4 + q] = B4[(size_t)(d0 + k) * 4 + q];

    __syncthreads();

    #pragma unroll
    for (int ti = 0; ti < TPB; ++ti) {
        int gtok = base_tok + ti;
        if (gtok >= n_tokens) break;
        int tok = sT[ti];

        // a-vector (broadcast LDS reads — conflict-free)
        float a[R];
        #pragma unroll
        for (int r = 0; r < R; ++r) a[r] = sA[ti][r];

        const float4* e4 = reinterpret_cast<const float4*>(emb + (size_t)tok * DIM);
        float4 e = e4[tid];

        float acc[4];
        #pragma unroll
        for (int k = 0; k < 4; ++k) {
            float s = 0.0f;
            #pragma unroll
            for (int q = 0; q < 4; ++q) {
                float4 bb = b[k * 4 + q];
                s += bb.x * a[q * 4 + 0];
                s += bb.y * a[q * 4 + 1];
                s += bb.z * a[q * 4 + 2];
                s += bb.w * a[q * 4 + 3];
            }
            acc[k] = s;
        }

        float4 res;
        res.x = e.x + SCALING * acc[0];
        res.y = e.y + SCALING * acc[1];
        res.z = e.z + SCALING * acc[2];
        res.w = e.w + SCALING * acc[3];

        float4* o4 = reinterpret_cast<float4*>(out + (size_t)gtok * DIM);
        o4[tid] = res;
    }
}

extern "C" void kernel_launch(void* const* d_in, const int* in_sizes, int n_in,
                              void* d_out, int out_size, void* d_ws, size_t ws_size,
                              hipStream_t stream) {
    const int*   ids = (const int*)  d_in[0];   // [4, 4096]
    const float* emb = (const float*)d_in[1];   // [VOCAB, DIM]
    const float* A   = (const float*)d_in[2];   // [R, VOCAB]
    const float* B   = (const float*)d_in[3];   // [DIM, R]
    float*       out = (float*)d_out;

    const int n_tokens = in_sizes[0];           // 16384
    const int grid = (n_tokens + TPB - 1) / TPB;

    adapted_embedding_kernel<<<grid, 256, 0, stream>>>(ids, emb, A, B, out, n_tokens);
}

// Round 4
// 287.355 us; speedup vs baseline: 1.0436x; 1.0436x over previous
//
#include <hip/hip_runtime.h>
#include <hip/hip_bf16.h>

#define VOCAB 50257
#define DIM   1024
#define R     16
#define SCALING 2.0f
#define TPB   16   // tokens per block (TPB * R == 256 == blockDim)

typedef float floatx4 __attribute__((ext_vector_type(4)));  // native vec for nontemporal builtin

__global__ __launch_bounds__(256, 4) void adapted_embedding_kernel(
    const int*   __restrict__ ids,
    const float* __restrict__ emb,
    const float* __restrict__ A,    // [R, VOCAB]
    const float* __restrict__ B,    // [DIM, R]
    float*       __restrict__ out,  // [n_tokens, DIM]
    int n_tokens)
{
    __shared__ float sA[TPB][R];
    __shared__ int   sT[TPB];

    const int tid      = threadIdx.x;
    const int base_tok = blockIdx.x * TPB;

    // Stage token ids (16 lanes)
    if (tid < TPB) {
        int g = base_tok + tid;
        sT[tid] = (g < n_tokens) ? ids[g] : 0;
    }
    __syncthreads();

    // Stage lora_A columns: all 256 lanes load exactly one scalar
    {
        int ti = tid >> 4;     // tid / R
        int r  = tid & 15;     // tid % R
        sA[ti][r] = A[(size_t)r * VOCAB + sT[ti]];
    }

    // Each thread owns d in [4*tid, 4*tid+4): its 4 lora_B rows (64 floats)
    const int d0 = tid * 4;
    const float4* B4 = reinterpret_cast<const float4*>(B);
    float4 b[16];
    #pragma unroll
    for (int k = 0; k < 4; ++k)
        #pragma unroll
        for (int q = 0; q < 4; ++q)
            b[k * 4 + q] = B4[(size_t)(d0 + k) * 4 + q];

    __syncthreads();

    #pragma unroll
    for (int ti = 0; ti < TPB; ++ti) {
        int gtok = base_tok + ti;
        if (gtok >= n_tokens) break;
        int tok = sT[ti];

        // a-vector (broadcast LDS reads — conflict-free)
        float a[R];
        #pragma unroll
        for (int r = 0; r < R; ++r) a[r] = sA[ti][r];

        const float4* e4 = reinterpret_cast<const float4*>(emb + (size_t)tok * DIM);
        float4 e = e4[tid];

        float acc[4];
        #pragma unroll
        for (int k = 0; k < 4; ++k) {
            float s = 0.0f;
            #pragma unroll
            for (int q = 0; q < 4; ++q) {
                float4 bb = b[k * 4 + q];
                s += bb.x * a[q * 4 + 0];
                s += bb.y * a[q * 4 + 1];
                s += bb.z * a[q * 4 + 2];
                s += bb.w * a[q * 4 + 3];
            }
            acc[k] = s;
        }

        floatx4 res;
        res.x = e.x + SCALING * acc[0];
        res.y = e.y + SCALING * acc[1];
        res.z = e.z + SCALING * acc[2];
        res.w = e.w + SCALING * acc[3];

        // Non-temporal: don't let the 67 MB output stream evict emb from L2/L3
        floatx4* o4 = reinterpret_cast<floatx4*>(out + (size_t)gtok * DIM);
        __builtin_nontemporal_store(res, &o4[tid]);
    }
}

extern "C" void kernel_launch(void* const* d_in, const int* in_sizes, int n_in,
                              void* d_out, int out_size, void* d_ws, size_t ws_size,
                              hipStream_t stream) {
    const int*   ids = (const int*)  d_in[0];   // [4, 4096]
    const float* emb = (const float*)d_in[1];   // [VOCAB, DIM]
    const float* A   = (const float*)d_in[2];   // [R, VOCAB]
    const float* B   = (const float*)d_in[3];   // [DIM, R]
    float*       out = (float*)d_out;

    const int n_tokens = in_sizes[0];           // 16384
    const int grid = (n_tokens + TPB - 1) / TPB;

    adapted_embedding_kernel<<<grid, 256, 0, stream>>>(ids, emb, A, B, out, n_tokens);
}

// Round 5
// 284.124 us; speedup vs baseline: 1.0554x; 1.0114x over previous
//
#include <hip/hip_runtime.h>
#include <hip/hip_bf16.h>

#define VOCAB 50257
#define DIM   1024
#define R     16
#define SCALING 2.0f
#define TPB   32   // tokens per block

typedef float floatx4 __attribute__((ext_vector_type(4)));  // native vec for nontemporal builtin

__global__ __launch_bounds__(256, 4) void adapted_embedding_kernel(
    const int*   __restrict__ ids,
    const float* __restrict__ emb,
    const float* __restrict__ A,    // [R, VOCAB]
    const float* __restrict__ B,    // [DIM, R]
    float*       __restrict__ out,  // [n_tokens, DIM]
    int n_tokens)
{
    __shared__ float sA[TPB][R];

    const int tid      = threadIdx.x;
    const int base_tok = blockIdx.x * TPB;

    // Stage lora_A columns: 512 scalars, each of 256 lanes loads 2.
    // ids[] reads are 16-way same-line redundant (L1-hot); no sT/barrier needed.
    {
        int ti = tid >> 4;          // 0..15
        int r  = tid & 15;
        int g0 = base_tok + ti;
        int g1 = base_tok + ti + 16;
        int t0 = (g0 < n_tokens) ? ids[g0] : 0;
        int t1 = (g1 < n_tokens) ? ids[g1] : 0;
        sA[ti][r]      = A[(size_t)r * VOCAB + t0];
        sA[ti + 16][r] = A[(size_t)r * VOCAB + t1];
    }

    // Each thread owns d in [4*tid, 4*tid+4): its 4 lora_B rows (64 floats)
    const int d0 = tid * 4;
    const float4* B4 = reinterpret_cast<const float4*>(B);
    float4 b[16];
    #pragma unroll
    for (int k = 0; k < 4; ++k)
        #pragma unroll
        for (int q = 0; q < 4; ++q)
            b[k * 4 + q] = B4[(size_t)(d0 + k) * 4 + q];

    __syncthreads();

    // 1-deep prefetch of the first emb row (token id is wave-uniform -> s_load)
    float4 e;
    {
        int tok0 = (base_tok < n_tokens) ? ids[base_tok] : 0;
        e = reinterpret_cast<const float4*>(emb + (size_t)tok0 * DIM)[tid];
    }

    #pragma unroll
    for (int ti = 0; ti < TPB; ++ti) {
        int gtok = base_tok + ti;
        if (gtok >= n_tokens) break;

        float4 cur = e;
        if (ti + 1 < TPB && gtok + 1 < n_tokens) {
            int ntok = ids[gtok + 1];   // wave-uniform scalar load
            e = reinterpret_cast<const float4*>(emb + (size_t)ntok * DIM)[tid];
        }

        // a-vector (broadcast LDS reads — conflict-free)
        float a[R];
        #pragma unroll
        for (int r = 0; r < R; ++r) a[r] = sA[ti][r];

        float acc[4];
        #pragma unroll
        for (int k = 0; k < 4; ++k) {
            float s = 0.0f;
            #pragma unroll
            for (int q = 0; q < 4; ++q) {
                float4 bb = b[k * 4 + q];
                s += bb.x * a[q * 4 + 0];
                s += bb.y * a[q * 4 + 1];
                s += bb.z * a[q * 4 + 2];
                s += bb.w * a[q * 4 + 3];
            }
            acc[k] = s;
        }

        floatx4 res;
        res.x = cur.x + SCALING * acc[0];
        res.y = cur.y + SCALING * acc[1];
        res.z = cur.z + SCALING * acc[2];
        res.w = cur.w + SCALING * acc[3];

        // Non-temporal: don't let the 67 MB output stream evict emb from L2/L3
        floatx4* o4 = reinterpret_cast<floatx4*>(out + (size_t)gtok * DIM);
        __builtin_nontemporal_store(res, &o4[tid]);
    }
}

extern "C" void kernel_launch(void* const* d_in, const int* in_sizes, int n_in,
                              void* d_out, int out_size, void* d_ws, size_t ws_size,
                              hipStream_t stream) {
    const int*   ids = (const int*)  d_in[0];   // [4, 4096]
    const float* emb = (const float*)d_in[1];   // [VOCAB, DIM]
    const float* A   = (const float*)d_in[2];   // [R, VOCAB]
    const float* B   = (const float*)d_in[3];   // [DIM, R]
    float*       out = (float*)d_out;

    const int n_tokens = in_sizes[0];           // 16384
    const int grid = (n_tokens + TPB - 1) / TPB;

    adapted_embedding_kernel<<<grid, 256, 0, stream>>>(ids, emb, A, B, out, n_tokens);
}